// Round 1
// baseline (567.067 us; speedup 1.0000x reference)
//
#include <hip/hip_runtime.h>

typedef __bf16 bf16x8 __attribute__((ext_vector_type(8)));
typedef float f32x4 __attribute__((ext_vector_type(4)));

// ---------- helpers ----------
__device__ __forceinline__ unsigned short f2bf(float f) {
    unsigned u = __builtin_bit_cast(unsigned, f);
    u += 0x7FFFu + ((u >> 16) & 1u);           // RNE
    return (unsigned short)(u >> 16);
}

__device__ __forceinline__ void gload16(void* lds, const void* g) {
    __builtin_amdgcn_global_load_lds((const __attribute__((address_space(1))) void*)g,
                                     (__attribute__((address_space(3))) void*)lds,
                                     16, 0, 0);
}

// ---------- kernel 1: fp32 -> bf16 elementwise ----------
__global__ void k_cvt(const float* __restrict__ in, unsigned short* __restrict__ out, int n8) {
    int i = blockIdx.x * blockDim.x + threadIdx.x;
    if (i >= n8) return;
    float4 a = ((const float4*)in)[i * 2];
    float4 b = ((const float4*)in)[i * 2 + 1];
    ushort4 r0 = { f2bf(a.x), f2bf(a.y), f2bf(a.z), f2bf(a.w) };
    ushort4 r1 = { f2bf(b.x), f2bf(b.y), f2bf(b.z), f2bf(b.w) };
    ((ushort4*)out)[i * 2]     = r0;
    ((ushort4*)out)[i * 2 + 1] = r1;
}

// ---------- kernel 2: fp32 [K][N] -> bf16 [N][K] (transpose + convert) ----------
__global__ void k_transpose(const float* __restrict__ in, unsigned short* __restrict__ out,
                            int K, int N) {
    __shared__ float tile[32][33];
    int n0 = blockIdx.x * 32, k0 = blockIdx.y * 32;
    int tx = threadIdx.x, ty = threadIdx.y;   // (32, 8)
#pragma unroll
    for (int i = 0; i < 32; i += 8)
        tile[ty + i][tx] = in[(size_t)(k0 + ty + i) * N + n0 + tx];
    __syncthreads();
#pragma unroll
    for (int i = 0; i < 32; i += 8)
        out[(size_t)(n0 + ty + i) * K + k0 + tx] = f2bf(tile[tx][ty + i]);
}

// ---------- kernel 3/5: bf16 GEMM, A[M][K] * Bt[N][K]^T ----------
// MODE 0: QKV projection, RoPE epilogue -> qkvo (q,k) + vto (v transposed)
// MODE 1: output projection, fp32 epilogue -> fout
template <int MODE>
__global__ __launch_bounds__(256) void k_gemm(
    const unsigned short* __restrict__ A,
    const unsigned short* __restrict__ Bt,
    int N,
    unsigned short* __restrict__ qkvo,
    unsigned short* __restrict__ vto,
    const float* __restrict__ cosT,
    const float* __restrict__ sinT,
    float* __restrict__ fout)
{
    __shared__ unsigned short As[128 * 32];   // [m][k]
    __shared__ unsigned short Bs[128 * 32];   // [n][k]
    const int K = 4096;
    int tid = threadIdx.x, wid = tid >> 6, lane = tid & 63;
    int lr = lane & 15, lg = lane >> 4;
    int m0 = blockIdx.y * 128, n0 = blockIdx.x * 128;
    int wm = (wid >> 1) * 64, wn = (wid & 1) * 64;

    f32x4 acc[4][4] = {};

    int ca = wid * 64 + lane;          // chunk id (16B chunks), set1
    int am = ca >> 2;                  // row within 64-row half
    int ak = (ca & 3) * 8;             // k offset within BK=32
    const unsigned short* Ap1 = A  + (size_t)(m0 + am)      * K + ak;
    const unsigned short* Ap2 = A  + (size_t)(m0 + am + 64) * K + ak;
    const unsigned short* Bp1 = Bt + (size_t)(n0 + am)      * K + ak;
    const unsigned short* Bp2 = Bt + (size_t)(n0 + am + 64) * K + ak;
    unsigned short* Ad1 = &As[(wid * 64) * 8];
    unsigned short* Ad2 = &As[(256 + wid * 64) * 8];
    unsigned short* Bd1 = &Bs[(wid * 64) * 8];
    unsigned short* Bd2 = &Bs[(256 + wid * 64) * 8];

    for (int k0 = 0; k0 < K; k0 += 32) {
        gload16(Ad1, Ap1 + k0);
        gload16(Ad2, Ap2 + k0);
        gload16(Bd1, Bp1 + k0);
        gload16(Bd2, Bp2 + k0);
        __syncthreads();
        bf16x8 af[4], bfr[4];
#pragma unroll
        for (int i = 0; i < 4; i++)
            af[i] = *(const bf16x8*)&As[(wm + i * 16 + lr) * 32 + lg * 8];
#pragma unroll
        for (int i = 0; i < 4; i++)
            bfr[i] = *(const bf16x8*)&Bs[(wn + i * 16 + lr) * 32 + lg * 8];
#pragma unroll
        for (int i = 0; i < 4; i++)
#pragma unroll
            for (int j = 0; j < 4; j++)
                acc[i][j] = __builtin_amdgcn_mfma_f32_16x16x32_bf16(af[i], bfr[j], acc[i][j], 0, 0, 0);
        __syncthreads();
    }

    if (MODE == 0) {
        // columns: [0,4096) q | [4096,5120) k | [5120,6144) v  (block-uniform type)
#pragma unroll
        for (int j = 0; j < 4; j++) {
            int ng = n0 + wn + j * 16 + lr;
            int d = ng & 127;
            bool isv = (ng >= 5120);
#pragma unroll
            for (int i = 0; i < 4; i++) {
#pragma unroll
                for (int r = 0; r < 4; r++) {
                    int sg = m0 + wm + i * 16 + lg * 4 + r;
                    float v = acc[i][j][r];
                    float part = __shfl_xor(v, 1, 64);   // paired rope element (col^1)
                    if (!isv) {
                        float cc = cosT[sg * 64 + (d >> 1)];
                        float ss = sinT[sg * 64 + (d >> 1)];
                        v = (d & 1) ? fmaf(part, ss, v * cc) : fmaf(-part, ss, v * cc);
                        qkvo[(size_t)sg * 6144 + ng] = f2bf(v);
                    } else {
                        vto[(size_t)(ng - 5120) * 2048 + sg] = f2bf(v);
                    }
                }
            }
        }
    } else {
#pragma unroll
        for (int j = 0; j < 4; j++) {
            int ng = n0 + wn + j * 16 + lr;
#pragma unroll
            for (int i = 0; i < 4; i++) {
#pragma unroll
                for (int r = 0; r < 4; r++) {
                    int sg = m0 + wm + i * 16 + lg * 4 + r;
                    fout[(size_t)sg * 4096 + ng] = acc[i][j][r];
                }
            }
        }
    }
}

// ---------- kernel 4: causal GQA flash attention ----------
// qkv: [2048][6144] bf16 (q roped | k roped | unused v cols)
// vt:  [1024][2048] bf16 (v transposed: [kv_head*128+d][s])
// ao:  [2048][4096] bf16 attention output
__global__ __launch_bounds__(256) void k_attn(
    const unsigned short* __restrict__ qkv,
    const unsigned short* __restrict__ vt,
    unsigned short* __restrict__ ao)
{
    __shared__ unsigned short Ks[32 * 128];   // [kp][d], chunks xor-swizzled by (kp&7)
    __shared__ unsigned short Vs[128 * 32];   // [d][kp], chunks xor-swizzled by (d&3)
    __shared__ unsigned short Ps[4 * 16 * 32];

    int tid = threadIdx.x, w = tid >> 6, lane = tid & 63;
    int lr = lane & 15, lg = lane >> 4;
    int h = blockIdx.x & 31;
    int qt = 31 - (blockIdx.x >> 5);          // heavy q-tiles first
    int q0 = qt * 64, kvh = h >> 2;

    // Q fragments in registers (wave w owns rows q0+w*16 .. +15)
    int qrow = q0 + w * 16 + lr;
    const unsigned short* qp = qkv + (size_t)qrow * 6144 + h * 128 + lg * 8;
    bf16x8 aq[4];
#pragma unroll
    for (int kb = 0; kb < 4; kb++) aq[kb] = *(const bf16x8*)(qp + kb * 32);

    f32x4 o[8] = {};
    float m[4], l[4];
#pragma unroll
    for (int r = 0; r < 4; r++) { m[r] = -1e30f; l[r] = 0.f; }
    constexpr float SCL2 = 0.08838834764831845f * 1.44269504088896340f; // 1/sqrt(128)*log2(e)

    // staging address precompute (set2 = set1 + fixed stride; swizzle invariant)
    int c1 = w * 64 + lane;
    int kp1 = c1 >> 4, pc1 = c1 & 15;
    const unsigned short* kgp = qkv + (size_t)kp1 * 6144 + 4096 + kvh * 128 + (pc1 ^ (kp1 & 7)) * 8;
    int d1 = c1 >> 2, pcv = c1 & 3;
    const unsigned short* vgp = vt + (size_t)(kvh * 128 + d1) * 2048 + (pcv ^ (d1 & 3)) * 8;
    unsigned short* Kd1 = &Ks[(w * 64) * 8];
    unsigned short* Kd2 = &Ks[(256 + w * 64) * 8];
    unsigned short* Vd1 = &Vs[(w * 64) * 8];
    unsigned short* Vd2 = &Vs[(256 + w * 64) * 8];

    int nt = 2 * (qt + 1);
    for (int t = 0; t < nt; ++t) {
        int kp0 = t * 32;
        gload16(Kd1, kgp + (size_t)kp0 * 6144);
        gload16(Kd2, kgp + (size_t)kp0 * 6144 + (size_t)16 * 6144);
        gload16(Vd1, vgp + kp0);
        gload16(Vd2, vgp + kp0 + 64 * 2048);
        __syncthreads();

        if (kp0 <= q0 + w * 16 + 15) {      // wave has unmasked work
            f32x4 sc[2] = {};
#pragma unroll
            for (int cb = 0; cb < 2; ++cb) {
                int kp = cb * 16 + lr;
#pragma unroll
                for (int kb = 0; kb < 4; ++kb) {
                    int dcl = kb * 4 + lg;
                    bf16x8 bk = *(const bf16x8*)&Ks[kp * 128 + ((dcl ^ (kp & 7)) * 8)];
                    sc[cb] = __builtin_amdgcn_mfma_f32_16x16x32_bf16(aq[kb], bk, sc[cb], 0, 0, 0);
                }
            }
            if (kp0 + 31 > q0 + w * 16) {   // diagonal tile: causal mask
#pragma unroll
                for (int cb = 0; cb < 2; ++cb) {
                    int kpg = kp0 + cb * 16 + lr;
#pragma unroll
                    for (int r = 0; r < 4; r++) {
                        int qg = q0 + w * 16 + lg * 4 + r;
                        if (kpg > qg) sc[cb][r] = -1e30f;
                    }
                }
            }
            // online softmax (rows live across 16 lanes of same lg)
            float tm[4];
#pragma unroll
            for (int r = 0; r < 4; r++) tm[r] = fmaxf(sc[0][r], sc[1][r]);
#pragma unroll
            for (int off = 1; off < 16; off <<= 1)
#pragma unroll
                for (int r = 0; r < 4; r++) tm[r] = fmaxf(tm[r], __shfl_xor(tm[r], off, 64));
            float al[4], rs[4];
#pragma unroll
            for (int r = 0; r < 4; r++) {
                float mn = fmaxf(m[r], tm[r]);
                al[r] = exp2f((m[r] - mn) * SCL2);
                m[r] = mn;
                rs[r] = 0.f;
            }
#pragma unroll
            for (int cb = 0; cb < 2; cb++)
#pragma unroll
                for (int r = 0; r < 4; r++) {
                    float p = exp2f((sc[cb][r] - m[r]) * SCL2);
                    sc[cb][r] = p;
                    rs[r] += p;
                }
#pragma unroll
            for (int off = 1; off < 16; off <<= 1)
#pragma unroll
                for (int r = 0; r < 4; r++) rs[r] += __shfl_xor(rs[r], off, 64);
#pragma unroll
            for (int r = 0; r < 4; r++) l[r] = l[r] * al[r] + rs[r];
#pragma unroll
            for (int db = 0; db < 8; db++)
#pragma unroll
                for (int r = 0; r < 4; r++) o[db][r] *= al[r];
            // P -> per-wave LDS (swizzled), re-read as A-fragments
#pragma unroll
            for (int cb = 0; cb < 2; cb++)
#pragma unroll
                for (int r = 0; r < 4; r++) {
                    int q = lg * 4 + r, kp = cb * 16 + lr;
                    Ps[w * 512 + q * 32 + (((kp >> 3) ^ (q & 3)) * 8) + (kp & 7)] = f2bf(sc[cb][r]);
                }
            asm volatile("s_waitcnt lgkmcnt(0)" ::: "memory");
            bf16x8 pa = *(const bf16x8*)&Ps[w * 512 + lr * 32 + ((lg ^ (lr & 3)) * 8)];
#pragma unroll
            for (int db = 0; db < 8; db++) {
                int d = db * 16 + lr;
                bf16x8 bv = *(const bf16x8*)&Vs[d * 32 + ((lg ^ (d & 3)) * 8)];
                o[db] = __builtin_amdgcn_mfma_f32_16x16x32_bf16(pa, bv, o[db], 0, 0, 0);
            }
        }
        __syncthreads();
    }

#pragma unroll
    for (int r = 0; r < 4; r++) l[r] = 1.0f / l[r];
#pragma unroll
    for (int db = 0; db < 8; db++)
#pragma unroll
        for (int r = 0; r < 4; r++) {
            int qg = q0 + w * 16 + lg * 4 + r;
            ao[(size_t)qg * 4096 + h * 128 + db * 16 + lr] = f2bf(o[db][r] * l[r]);
        }
}

// ---------- launcher ----------
extern "C" void kernel_launch(void* const* d_in, const int* in_sizes, int n_in,
                              void* d_out, int out_size, void* d_ws, size_t ws_size,
                              hipStream_t stream) {
    const float* hs   = (const float*)d_in[0];
    const float* wq   = (const float*)d_in[1];
    const float* wk   = (const float*)d_in[2];
    const float* wv   = (const float*)d_in[3];
    const float* wo   = (const float*)d_in[4];
    const float* cosT = (const float*)d_in[5];
    const float* sinT = (const float*)d_in[6];
    float* out = (float*)d_out;

    unsigned short* hsb   = (unsigned short*)d_ws;                 // 2048*4096
    unsigned short* wqkvT = hsb   + (size_t)2048 * 4096;           // 6144*4096
    unsigned short* woT   = wqkvT + (size_t)6144 * 4096;           // 4096*4096
    unsigned short* qkvb  = woT   + (size_t)4096 * 4096;           // 2048*6144
    unsigned short* vtb   = qkvb  + (size_t)2048 * 6144;           // 1024*2048
    unsigned short* attnb = vtb   + (size_t)1024 * 2048;           // 2048*4096

    k_cvt<<<4096, 256, 0, stream>>>(hs, hsb, 1048576);
    dim3 tb(32, 8);
    k_transpose<<<dim3(128, 128), tb, 0, stream>>>(wq, wqkvT, 4096, 4096);
    k_transpose<<<dim3(32, 128),  tb, 0, stream>>>(wk, wqkvT + (size_t)4096 * 4096, 4096, 1024);
    k_transpose<<<dim3(32, 128),  tb, 0, stream>>>(wv, wqkvT + (size_t)5120 * 4096, 4096, 1024);
    k_transpose<<<dim3(128, 128), tb, 0, stream>>>(wo, woT, 4096, 4096);

    k_gemm<0><<<dim3(48, 16), 256, 0, stream>>>(hsb, wqkvT, 6144, qkvb, vtb, cosT, sinT, nullptr);
    k_attn<<<1024, 256, 0, stream>>>(qkvb, vtb, attnb);
    k_gemm<1><<<dim3(32, 16), 256, 0, stream>>>(attnb, woT, 4096, nullptr, nullptr, nullptr, nullptr, out);
}